// Round 9
// baseline (917.484 us; speedup 1.0000x reference)
//
#include <hip/hip_runtime.h>
#include <hip/hip_fp16.h>

#define HID 1024
#define QCOLS 512
#define KP 2048   // physical K per operand: [hi(1024) | lo(1024)]
#define NT 48     // logical K' = 3072 = 48 tiles of 64

typedef _Float16 f16x8 __attribute__((ext_vector_type(8)));
typedef float f32x4 __attribute__((ext_vector_type(4)));

// ---- K0: transpose+convert+split both weights in one dispatch ----------------
__global__ void tconv_both(const float* __restrict__ w2, __half* __restrict__ w2t,
                           const float* __restrict__ w3, __half* __restrict__ w3t) {
  __shared__ float tile[32][33];
  const int z = blockIdx.z;
  const int N = z ? QCOLS : HID;
  if (blockIdx.x * 32 >= N) return;
  const float* src = z ? w3 : w2;
  __half* dst = z ? w3t : w2t;
  int n0 = blockIdx.x * 32, k0 = blockIdx.y * 32;
  int tx = threadIdx.x, ty = threadIdx.y;
  for (int i = ty; i < 32; i += 8)
    tile[i][tx] = src[(size_t)(k0 + i) * N + n0 + tx];
  __syncthreads();
  for (int i = ty; i < 32; i += 8) {
    float v = tile[tx][i] * 256.f;
    __half h = __float2half(v);
    size_t o = (size_t)(n0 + i) * KP + k0 + tx;
    dst[o] = h;
    dst[o + 1024] = __float2half(v - __half2float(h));
  }
}

// ---- K1: h1 = relu(yA @ w1 + b1) fp32, split to [hi|lo] f16 (x64) ------------
__global__ __launch_bounds__(256)
void h1k(const float* __restrict__ y, const float* __restrict__ w1,
         const float* __restrict__ b1, __half* __restrict__ h1,
         int row0, int nrows) {
  const int t = threadIdx.x & 127;
  const int rl = threadIdx.x >> 7;
  const long r = (long)blockIdx.x * 2 + rl;
  if (r >= nrows) return;
  const float* yr = y + (size_t)(row0 + r) * 17;
  float yv[8];
#pragma unroll
  for (int k = 0; k < 8; ++k) yv[k] = yr[k];
  const int c0 = t * 8;
  f32x4 a0 = *(const f32x4*)(b1 + c0);
  f32x4 a1 = *(const f32x4*)(b1 + c0 + 4);
#pragma unroll
  for (int k = 0; k < 8; ++k) {
    const f32x4 w0 = *(const f32x4*)(w1 + k * HID + c0);
    const f32x4 w1v = *(const f32x4*)(w1 + k * HID + c0 + 4);
#pragma unroll
    for (int j = 0; j < 4; ++j) {
      a0[j] = fmaf(yv[k], w0[j], a0[j]);
      a1[j] = fmaf(yv[k], w1v[j], a1[j]);
    }
  }
  f16x8 hi, lo;
#pragma unroll
  for (int j = 0; j < 8; ++j) {
    float v = fmaxf(j < 4 ? a0[j] : a1[j - 4], 0.f) * 64.f;
    _Float16 h = (_Float16)v;
    hi[j] = h;
    lo[j] = (_Float16)(v - (float)h);
  }
  *(f16x8*)(h1 + (size_t)r * KP + c0) = hi;
  *(f16x8*)(h1 + (size_t)r * KP + c0 + 1024) = lo;
}

// ---- 256x128 split-f16 GEMM, 3-slot ring, 2 blocks/CU ------------------------
// Slot = [A 16KB | B 8KB] = 24KB; 3 slots = 72KB -> 2 blocks/CU (TLP overlap).
// Phase p: ds_read slot p%3, stage slot (p+2)%3, barrier, 16 MFMA, vmcnt(3), barrier.
// ACT 0: relu -> split f16 [hi|lo] (x64). ACT 1: softplus -> f32.
template <int ACT>
__device__ __forceinline__
void gemm_ring_body(const __half* __restrict__ A, const __half* __restrict__ Bt,
                    const float* __restrict__ bias, __half* __restrict__ Co,
                    float* __restrict__ Cf, int ldc) {
  constexpr int SLOT = 16384 + 8192;
  __shared__ char lds[3 * SLOT];
  const int tid = threadIdx.x;
  const int lane = tid & 63, wave = tid >> 6;
  const int p = lane & 15, ql = lane >> 4;
  const int wm = wave >> 2, wn = wave & 3;

  // XCD-bijective block swizzle (m204)
  const int gx = gridDim.x, nwg = gx * gridDim.y;
  const int bid = blockIdx.y * gx + blockIdx.x;
  const int q8 = nwg >> 3, r8 = nwg & 7;
  const int xcd = bid & 7, lxi = bid >> 3;
  const int swz = (xcd < r8 ? xcd * (q8 + 1) : r8 * (q8 + 1) + (xcd - r8) * q8) + lxi;
  const size_t row_blk = (size_t)(swz / gx) * 256;
  const size_t col_blk = (size_t)(swz % gx) * 128;

  int a_off[8], b_off[2];
#pragma unroll
  for (int m = 0; m < 8; ++m) {
    int r = wm * 128 + m * 16 + p;
    a_off[m] = r * 64 + ((ql ^ ((r >> 1) & 3)) << 4);
  }
#pragma unroll
  for (int n = 0; n < 2; ++n) {
    int r = wn * 32 + n * 16 + p;
    b_off[n] = r * 64 + ((ql ^ ((r >> 1) & 3)) << 4);
  }

  const int idx0 = tid, idx1 = tid + 512;
  const int sr0 = idx0 >> 2, sq0 = (idx0 & 3) ^ ((sr0 >> 1) & 3);
  const int sr1 = idx1 >> 2, sq1 = (idx1 & 3) ^ ((sr1 >> 1) & 3);

  auto gload = [&](const __half* g, char* l) {
    __builtin_amdgcn_global_load_lds((__attribute__((address_space(1))) void*)g,
        (__attribute__((address_space(3))) void*)l, 16, 0, 0);
  };

  // stage ring phase q into slot: tile q>>1 (clamped), K-half q&1
  auto stage = [&](int q, int slot) {
    int kt = q >> 1; if (kt > NT - 1) kt = NT - 1;
    const int h = q & 1;
    const int lk = kt * 64;
    const int ak = ((lk >= 2048) ? 1024 : 0) + (lk & 1023) + h * 32;
    const int bk = ((lk >= 1024 && lk < 2048) ? 1024 : 0) + (lk & 1023) + h * 32;
    char* base = lds + slot * SLOT;
    char* pb = base + 16384;
    gload(A + (row_blk + sr0) * (size_t)KP + ak + sq0 * 8, base + idx0 * 16);
    gload(A + (row_blk + sr1) * (size_t)KP + ak + sq1 * 8, base + idx1 * 16);
    gload(Bt + (col_blk + sr0) * (size_t)KP + bk + sq0 * 8, pb + idx0 * 16);
  };

  // prologue: stages 0,1 issued; certify slot 0 (leave stage 1's 3 loads)
  stage(0, 0);
  stage(1, 1);
  asm volatile("s_waitcnt vmcnt(3)" ::: "memory");
  __builtin_amdgcn_s_barrier();

  f32x4 acc[8][2] = {};

  int cur = 0;  // = ph % 3
  for (int ph = 0; ph < NT * 2; ++ph) {
    const char* base = lds + cur * SLOT;
    const char* pB = base + 16384;
    f16x8 af[8], bfr[2];
#pragma unroll
    for (int m = 0; m < 8; ++m) af[m] = *(const f16x8*)(base + a_off[m]);
#pragma unroll
    for (int n = 0; n < 2; ++n) bfr[n] = *(const f16x8*)(pB + b_off[n]);
    const int nslot = cur == 0 ? 2 : cur - 1;  // (ph+2)%3
    stage(ph + 2, nslot);
    __builtin_amdgcn_sched_barrier(0);
    __builtin_amdgcn_s_barrier();
    __builtin_amdgcn_sched_barrier(0);
    __builtin_amdgcn_s_setprio(1);
#pragma unroll
    for (int m = 0; m < 8; ++m)
#pragma unroll
      for (int n = 0; n < 2; ++n)
        acc[m][n] = __builtin_amdgcn_mfma_f32_16x16x32_f16(af[m], bfr[n], acc[m][n], 0, 0, 0);
    __builtin_amdgcn_s_setprio(0);
    asm volatile("s_waitcnt vmcnt(3)" ::: "memory");  // certify slot ph+1
    __builtin_amdgcn_sched_barrier(0);
    __builtin_amdgcn_s_barrier();
    __builtin_amdgcn_sched_barrier(0);
    cur = cur == 2 ? 0 : cur + 1;
  }

  const float unscale = 1.f / 16384.f;
#pragma unroll
  for (int n = 0; n < 2; ++n) {
    const size_t col = col_blk + wn * 32 + n * 16 + p;
    const float bv = bias[col];
#pragma unroll
    for (int m = 0; m < 8; ++m) {
      const size_t row0 = row_blk + wm * 128 + m * 16 + ql * 4;
#pragma unroll
      for (int j = 0; j < 4; ++j) {
        float v = acc[m][n][j] * unscale + bv;
        const size_t o = (row0 + j) * (size_t)ldc + col;
        if constexpr (ACT == 0) {
          float r = fmaxf(v, 0.f) * 64.f;
          __half hh = __float2half(r);
          Co[o] = hh;
          Co[o + 1024] = __float2half(r - __half2float(hh));
        } else {
          float sp = fmaxf(v, 0.f) + log1pf(expf(-fabsf(v)));  // stable softplus
          Cf[o] = sp + 1e-6f;
        }
      }
    }
  }
}

__global__ __launch_bounds__(512, 4)
void g2relu(const __half* __restrict__ A, const __half* __restrict__ B,
            const float* __restrict__ bias, __half* __restrict__ Co) {
  gemm_ring_body<0>(A, B, bias, Co, nullptr, KP);
}

__global__ __launch_bounds__(512, 4)
void g3soft(const __half* __restrict__ A, const __half* __restrict__ B,
            const float* __restrict__ bias, float* __restrict__ Cf) {
  gemm_ring_body<1>(A, B, bias, nullptr, Cf, QCOLS);
}

// ---- K4: per-row piecewise-linear inverse + jacobian (np-order-matched) ------
__global__ __launch_bounds__(256)
void pwl_epi(const float* __restrict__ y, const float* __restrict__ q,
             float* __restrict__ out, int row0, int nrows) {
  const int wave = threadIdx.x >> 6, lane = threadIdx.x & 63;
  const int r = blockIdx.x * 4 + wave;
  if (r >= nrows) return;
  const float* yr = y + (size_t)(row0 + r) * 17;
  float* orow = out + (size_t)(row0 + r) * 17;
  const float* qr = q + (size_t)r * QCOLS;
  float prod_inv = 1.f;
#pragma unroll
  for (int t = 0; t < 8; ++t) {
    const float qv = qr[t * 64 + lane];
    float s = qv;
#pragma unroll
    for (int d = 1; d < 64; d <<= 1) {
      float u = __shfl_up(s, d);
      if (lane >= d) s += u;
    }
    const float total = __shfl(s, 63);
    const float sn = s / total;
    const float dnorm = total * 0.015625f;
    const float slope_l = qv / dnorm;
    const float yb = yr[8 + t];
    const unsigned long long m = __ballot(sn < yb);
    int bin = (int)__popcll(m);
    bin = bin > 63 ? 63 : bin;
    const float off_g = __shfl(sn, bin > 0 ? bin - 1 : 0);
    const float off = (bin == 0) ? 0.f : off_g;
    const float sl = __shfl(slope_l, bin);
    const float xB = (yb - off) / sl + (float)bin * 0.015625f;
    if (lane == t) orow[8 + t] = xB;
    prod_inv *= (1.f / sl);
  }
  if (lane < 8) orow[lane] = yr[lane];
  if (lane == 8) orow[16] = yr[16] * prod_inv;
}

// ---- launch ------------------------------------------------------------------
extern "C" void kernel_launch(void* const* d_in, const int* in_sizes, int n_in,
                              void* d_out, int out_size, void* d_ws, size_t ws_size,
                              hipStream_t stream) {
  const float* y  = (const float*)d_in[0];
  const float* w1 = (const float*)d_in[1];
  const float* b1 = (const float*)d_in[2];
  const float* w2 = (const float*)d_in[3];
  const float* b2 = (const float*)d_in[4];
  const float* w3 = (const float*)d_in[5];
  const float* b3 = (const float*)d_in[6];
  float* out = (float*)d_out;
  const long Btot = in_sizes[0] / 17;

  char* ws = (char*)d_ws;
  __half* w2t = (__half*)ws;                      // 4 MB  [1024][2048] hi|lo
  __half* w3t = (__half*)(ws + (4u << 20));       // 2 MB  [512][2048]  hi|lo
  const size_t fixed = (size_t)6 << 20;

  // Power-of-two chunks at 8 KB/row (h1 4 KB + h2 4 KB; q f32 aliases h1).
  const size_t avail = ws_size > fixed ? ws_size - fixed : 0;
  long maxrows = (long)(avail / 8192);
  long chunk = 256;
  for (long c = 65536; c >= 256; c >>= 1) {
    if (c <= maxrows && c <= Btot) { chunk = c; break; }
  }

  __half* h1buf = (__half*)(ws + fixed);
  __half* h2buf = (__half*)(ws + fixed + (size_t)chunk * 4096);
  float* qbuf = (float*)h1buf;  // h1 dead once g2relu finishes

  tconv_both<<<dim3(32, 32, 2), dim3(32, 8), 0, stream>>>(w2, w2t, w3, w3t);

  for (long row0 = 0; row0 < Btot; row0 += chunk) {
    const int nr = (int)((Btot - row0 < chunk) ? (Btot - row0) : chunk);
    h1k<<<(nr + 1) / 2, 256, 0, stream>>>(y, w1, b1, h1buf, (int)row0, nr);
    g2relu<<<dim3(HID / 128, nr / 256), 512, 0, stream>>>(h1buf, w2t, b2, h2buf);
    g3soft<<<dim3(QCOLS / 128, nr / 256), 512, 0, stream>>>(h2buf, w3t, b3, qbuf);
    pwl_epi<<<(nr + 3) / 4, 256, 0, stream>>>(y, qbuf, out, (int)row0, nr);
  }
}

// Round 10
// 890.095 us; speedup vs baseline: 1.0308x; 1.0308x over previous
//
#include <hip/hip_runtime.h>
#include <hip/hip_fp16.h>

#define HID 1024
#define QCOLS 512
#define KP 2048   // physical K per operand: [hi(1024) | lo(1024)]
#define NT 48     // logical K' = 3072 = 48 tiles of 64

typedef _Float16 f16x8 __attribute__((ext_vector_type(8)));
typedef float f32x4 __attribute__((ext_vector_type(4)));

// ---- K0: transpose+convert+split both weights in one dispatch ----------------
__global__ void tconv_both(const float* __restrict__ w2, __half* __restrict__ w2t,
                           const float* __restrict__ w3, __half* __restrict__ w3t) {
  __shared__ float tile[32][33];
  const int z = blockIdx.z;
  const int N = z ? QCOLS : HID;
  if (blockIdx.x * 32 >= N) return;
  const float* src = z ? w3 : w2;
  __half* dst = z ? w3t : w2t;
  int n0 = blockIdx.x * 32, k0 = blockIdx.y * 32;
  int tx = threadIdx.x, ty = threadIdx.y;
  for (int i = ty; i < 32; i += 8)
    tile[i][tx] = src[(size_t)(k0 + i) * N + n0 + tx];
  __syncthreads();
  for (int i = ty; i < 32; i += 8) {
    float v = tile[tx][i] * 256.f;
    __half h = __float2half(v);
    size_t o = (size_t)(n0 + i) * KP + k0 + tx;
    dst[o] = h;
    dst[o + 1024] = __float2half(v - __half2float(h));
  }
}

// ---- K1: h1 = relu(yA @ w1 + b1) fp32, split to [hi|lo] f16 (x64) ------------
__global__ __launch_bounds__(256)
void h1k(const float* __restrict__ y, const float* __restrict__ w1,
         const float* __restrict__ b1, __half* __restrict__ h1,
         int row0, int nrows) {
  const int t = threadIdx.x & 127;
  const int rl = threadIdx.x >> 7;
  const long r = (long)blockIdx.x * 2 + rl;
  if (r >= nrows) return;
  const float* yr = y + (size_t)(row0 + r) * 17;
  float yv[8];
#pragma unroll
  for (int k = 0; k < 8; ++k) yv[k] = yr[k];
  const int c0 = t * 8;
  f32x4 a0 = *(const f32x4*)(b1 + c0);
  f32x4 a1 = *(const f32x4*)(b1 + c0 + 4);
#pragma unroll
  for (int k = 0; k < 8; ++k) {
    const f32x4 w0 = *(const f32x4*)(w1 + k * HID + c0);
    const f32x4 w1v = *(const f32x4*)(w1 + k * HID + c0 + 4);
#pragma unroll
    for (int j = 0; j < 4; ++j) {
      a0[j] = fmaf(yv[k], w0[j], a0[j]);
      a1[j] = fmaf(yv[k], w1v[j], a1[j]);
    }
  }
  f16x8 hi, lo;
#pragma unroll
  for (int j = 0; j < 8; ++j) {
    float v = fmaxf(j < 4 ? a0[j] : a1[j - 4], 0.f) * 64.f;
    _Float16 h = (_Float16)v;
    hi[j] = h;
    lo[j] = (_Float16)(v - (float)h);
  }
  *(f16x8*)(h1 + (size_t)r * KP + c0) = hi;
  *(f16x8*)(h1 + (size_t)r * KP + c0 + 1024) = lo;
}

// ---- BMxBN split-f16 GEMM, 3-slot ring, ONE barrier + ONE vmcnt per phase ----
// Waves 2M x 4N, wave-tile (BM/2)x(BN/4). Slot = [A BM*64B | B BN*64B].
// Phase p: vmcnt(LPS) certifies slot p%3 (own loads issued in phase p-2);
// barrier (also guarantees all waves' reads of slot (p-1)%3 completed, since
// each wave's lgkm-guarded MFMA(p-1) precedes it); ds_read slot p%3; stage
// phase p+2 into slot (p+2)%3 == (p-1)%3 (freed); MFMA cluster.
// ACT 0: relu -> split f16 [hi|lo] (x64). ACT 1: softplus -> f32.
template <int ACT, int BM, int BN>
__device__ __forceinline__
void gemm1b_body(const __half* __restrict__ A, const __half* __restrict__ Bt,
                 const float* __restrict__ bias, __half* __restrict__ Co,
                 float* __restrict__ Cf, int ldc) {
  constexpr int MFRAG = BM / 32;        // per-wave 16-row frags
  constexpr int NFRAG = BN / 64;        // per-wave 16-col frags
  constexpr int SLOT = (BM + BN) * 64;  // bytes per ring slot
  constexpr int LA = BM / 128;          // A gloads per thread per stage
  constexpr int LB = BN / 128;
  constexpr int LPS = LA + LB;
  __shared__ char lds[3 * SLOT];
  const int tid = threadIdx.x;
  const int lane = tid & 63, wave = tid >> 6;
  const int p = lane & 15, ql = lane >> 4;
  const int wm = wave >> 2, wn = wave & 3;

  // XCD-bijective block swizzle (m204)
  const int gx = gridDim.x, nwg = gx * gridDim.y;
  const int bid = blockIdx.y * gx + blockIdx.x;
  const int q8 = nwg >> 3, r8 = nwg & 7;
  const int xcd = bid & 7, lxi = bid >> 3;
  const int swz = (xcd < r8 ? xcd * (q8 + 1) : r8 * (q8 + 1) + (xcd - r8) * q8) + lxi;
  const size_t row_blk = (size_t)(swz / gx) * BM;
  const size_t col_blk = (size_t)(swz % gx) * BN;

  int a_off[MFRAG], b_off[NFRAG];
#pragma unroll
  for (int m = 0; m < MFRAG; ++m) {
    int r = wm * (BM / 2) + m * 16 + p;
    a_off[m] = r * 64 + ((ql ^ ((r >> 1) & 3)) << 4);
  }
#pragma unroll
  for (int n = 0; n < NFRAG; ++n) {
    int r = wn * (BN / 4) + n * 16 + p;
    b_off[n] = r * 64 + ((ql ^ ((r >> 1) & 3)) << 4);
  }

  auto gload = [&](const __half* g, char* l) {
    __builtin_amdgcn_global_load_lds((__attribute__((address_space(1))) void*)g,
        (__attribute__((address_space(3))) void*)l, 16, 0, 0);
  };

  // stage ring phase q into slot: logical tile q>>1 (clamped), K-half q&1
  auto stage = [&](int q, int slot) {
    int kt = q >> 1; if (kt > NT - 1) kt = NT - 1;
    const int h = q & 1;
    const int lk = kt * 64;
    const int ak = ((lk >= 2048) ? 1024 : 0) + (lk & 1023) + h * 32;
    const int bk = ((lk >= 1024 && lk < 2048) ? 1024 : 0) + (lk & 1023) + h * 32;
    char* pa = lds + slot * SLOT;
    char* pb = pa + BM * 64;
#pragma unroll
    for (int i = 0; i < LA; ++i) {
      const int idx = tid + i * 512;
      const int sr = idx >> 2, sq = (idx & 3) ^ ((sr >> 1) & 3);
      gload(A + (row_blk + sr) * (size_t)KP + ak + sq * 8, pa + idx * 16);
    }
#pragma unroll
    for (int i = 0; i < LB; ++i) {
      const int idx = tid + i * 512;
      const int sr = idx >> 2, sq = (idx & 3) ^ ((sr >> 1) & 3);
      gload(Bt + (col_blk + sr) * (size_t)KP + bk + sq * 8, pb + idx * 16);
    }
  };

  // prologue: stages for phases 0,1 in flight
  stage(0, 0);
  stage(1, 1);

  f32x4 acc[MFRAG][NFRAG] = {};

  int cur = 0;  // = ph % 3
  for (int ph = 0; ph < NT * 2; ++ph) {
    // certify own loads of slot cur (issued 2 phases ago); newest LPS may fly
    if constexpr (LPS == 4) asm volatile("s_waitcnt vmcnt(4)" ::: "memory");
    else                    asm volatile("s_waitcnt vmcnt(3)" ::: "memory");
    __builtin_amdgcn_sched_barrier(0);
    __builtin_amdgcn_s_barrier();
    __builtin_amdgcn_sched_barrier(0);

    const char* base = lds + cur * SLOT;
    const char* pB = base + BM * 64;
    f16x8 af[MFRAG], bfr[NFRAG];
#pragma unroll
    for (int m = 0; m < MFRAG; ++m) af[m] = *(const f16x8*)(base + a_off[m]);
#pragma unroll
    for (int n = 0; n < NFRAG; ++n) bfr[n] = *(const f16x8*)(pB + b_off[n]);

    const int nslot = cur == 0 ? 2 : cur - 1;  // (ph+2)%3
    stage(ph + 2, nslot);
    __builtin_amdgcn_sched_barrier(0);

    __builtin_amdgcn_s_setprio(1);
#pragma unroll
    for (int m = 0; m < MFRAG; ++m)
#pragma unroll
      for (int n = 0; n < NFRAG; ++n)
        acc[m][n] = __builtin_amdgcn_mfma_f32_16x16x32_f16(af[m], bfr[n], acc[m][n], 0, 0, 0);
    __builtin_amdgcn_s_setprio(0);
    cur = cur == 2 ? 0 : cur + 1;
  }

  const float unscale = 1.f / 16384.f;
#pragma unroll
  for (int n = 0; n < NFRAG; ++n) {
    const size_t col = col_blk + wn * (BN / 4) + n * 16 + p;
    const float bv = bias[col];
#pragma unroll
    for (int m = 0; m < MFRAG; ++m) {
      const size_t row0 = row_blk + wm * (BM / 2) + m * 16 + ql * 4;
#pragma unroll
      for (int j = 0; j < 4; ++j) {
        float v = acc[m][n][j] * unscale + bv;
        const size_t o = (row0 + j) * (size_t)ldc + col;
        if constexpr (ACT == 0) {
          float r = fmaxf(v, 0.f) * 64.f;
          __half hh = __float2half(r);
          Co[o] = hh;
          Co[o + 1024] = __float2half(r - __half2float(hh));
        } else {
          float sp = fmaxf(v, 0.f) + log1pf(expf(-fabsf(v)));  // stable softplus
          Cf[o] = sp + 1e-6f;
        }
      }
    }
  }
}

__global__ __launch_bounds__(512, 2)
void g2relu(const __half* __restrict__ A, const __half* __restrict__ B,
            const float* __restrict__ bias, __half* __restrict__ Co) {
  gemm1b_body<0, 256, 256>(A, B, bias, Co, nullptr, KP);
}

__global__ __launch_bounds__(512, 4)
void g3soft(const __half* __restrict__ A, const __half* __restrict__ B,
            const float* __restrict__ bias, float* __restrict__ Cf) {
  gemm1b_body<1, 128, 256>(A, B, bias, nullptr, Cf, QCOLS);
}

// ---- K4: per-row piecewise-linear inverse + jacobian (np-order-matched) ------
__global__ __launch_bounds__(256)
void pwl_epi(const float* __restrict__ y, const float* __restrict__ q,
             float* __restrict__ out, int row0, int nrows) {
  const int wave = threadIdx.x >> 6, lane = threadIdx.x & 63;
  const int r = blockIdx.x * 4 + wave;
  if (r >= nrows) return;
  const float* yr = y + (size_t)(row0 + r) * 17;
  float* orow = out + (size_t)(row0 + r) * 17;
  const float* qr = q + (size_t)r * QCOLS;
  float prod_inv = 1.f;
#pragma unroll
  for (int t = 0; t < 8; ++t) {
    const float qv = qr[t * 64 + lane];
    float s = qv;
#pragma unroll
    for (int d = 1; d < 64; d <<= 1) {
      float u = __shfl_up(s, d);
      if (lane >= d) s += u;
    }
    const float total = __shfl(s, 63);
    const float sn = s / total;
    const float dnorm = total * 0.015625f;
    const float slope_l = qv / dnorm;
    const float yb = yr[8 + t];
    const unsigned long long m = __ballot(sn < yb);
    int bin = (int)__popcll(m);
    bin = bin > 63 ? 63 : bin;
    const float off_g = __shfl(sn, bin > 0 ? bin - 1 : 0);
    const float off = (bin == 0) ? 0.f : off_g;
    const float sl = __shfl(slope_l, bin);
    const float xB = (yb - off) / sl + (float)bin * 0.015625f;
    if (lane == t) orow[8 + t] = xB;
    prod_inv *= (1.f / sl);
  }
  if (lane < 8) orow[lane] = yr[lane];
  if (lane == 8) orow[16] = yr[16] * prod_inv;
}

// ---- launch ------------------------------------------------------------------
extern "C" void kernel_launch(void* const* d_in, const int* in_sizes, int n_in,
                              void* d_out, int out_size, void* d_ws, size_t ws_size,
                              hipStream_t stream) {
  const float* y  = (const float*)d_in[0];
  const float* w1 = (const float*)d_in[1];
  const float* b1 = (const float*)d_in[2];
  const float* w2 = (const float*)d_in[3];
  const float* b2 = (const float*)d_in[4];
  const float* w3 = (const float*)d_in[5];
  const float* b3 = (const float*)d_in[6];
  float* out = (float*)d_out;
  const long Btot = in_sizes[0] / 17;

  char* ws = (char*)d_ws;
  __half* w2t = (__half*)ws;                      // 4 MB  [1024][2048] hi|lo
  __half* w3t = (__half*)(ws + (4u << 20));       // 2 MB  [512][2048]  hi|lo
  const size_t fixed = (size_t)6 << 20;

  // Power-of-two chunks at 8 KB/row (h1 4 KB + h2 4 KB; q f32 aliases h1).
  const size_t avail = ws_size > fixed ? ws_size - fixed : 0;
  long maxrows = (long)(avail / 8192);
  long chunk = 256;
  for (long c = 65536; c >= 256; c >>= 1) {
    if (c <= maxrows && c <= Btot) { chunk = c; break; }
  }

  __half* h1buf = (__half*)(ws + fixed);
  __half* h2buf = (__half*)(ws + fixed + (size_t)chunk * 4096);
  float* qbuf = (float*)h1buf;  // h1 dead once g2relu finishes

  tconv_both<<<dim3(32, 32, 2), dim3(32, 8), 0, stream>>>(w2, w2t, w3, w3t);

  for (long row0 = 0; row0 < Btot; row0 += chunk) {
    const int nr = (int)((Btot - row0 < chunk) ? (Btot - row0) : chunk);
    h1k<<<(nr + 1) / 2, 256, 0, stream>>>(y, w1, b1, h1buf, (int)row0, nr);
    g2relu<<<dim3(HID / 256, nr / 256), 512, 0, stream>>>(h1buf, w2t, b2, h2buf);
    g3soft<<<dim3(QCOLS / 256, nr / 128), 512, 0, stream>>>(h2buf, w3t, b3, qbuf);
    pwl_epi<<<(nr + 3) / 4, 256, 0, stream>>>(y, qbuf, out, (int)row0, nr);
  }
}